// Round 4
// baseline (342.528 us; speedup 1.0000x reference)
//
#include <hip/hip_runtime.h>
#include <math.h>

#define B_ 4
#define D_ 32
#define H_ 192
#define W_ 192
#define HW_ (H_ * W_)

#define NT 5            // Taylor terms p = 1..5

#define TW 48           // 12 real col-groups; 16 quads incl. halo
#define TH 12
#define NTHR 192        // 3 waves; each thread: 1 s1 item + 1 s2 item
#define ZCHUNK 8
#define NP (ZCHUNK + 8) // 16 planes staged; iterations p = 0..16

#define RQ 16           // quads per R' row
#define RW 64           // words per R' row
#define R_PL (TH * RW)      // 768 words per term-plane
#define RBUF (NT * R_PL)    // 3840
// +16 pad: garbage-group (cg>=12) window reads overrun by <=15 words
#define SMEM_WORDS (2 * RBUF + 16)   // 7696 words = 30.8 KB

#define NTAPS (B_ * 9 * 15 * 15)

__device__ inline float4 f4fma(float c, float4 a, float4 d) {
    d.x = fmaf(c, a.x, d.x); d.y = fmaf(c, a.y, d.y);
    d.z = fmaf(c, a.z, d.z); d.w = fmaf(c, a.w, d.w);
    return d;
}
__device__ inline float4 f4add(float4 a, float4 b) {
    a.x += b.x; a.y += b.y; a.z += b.z; a.w += b.w; return a;
}
__device__ inline float rfl(float x) {
    return __int_as_float(__builtin_amdgcn_readfirstlane(__float_as_int(x)));
}

// h-first separable-Taylor blur, NO xt tile:
//   s1: h-conv reads x directly from global (aligned float4, L1-resident
//       within the iteration) -> R'[p&1] in LDS (5 term-planes, 12x64)
//   s2: w-conv + z-scatter from R'[(p-1)&1]
// 192-thread blocks, uniform roles (1 s1 + 1 s2 item per thread);
// ZCHUNK=8 -> 1024 blocks -> 4 blocks/CU -> 12 waves/CU for latency hiding.
__global__ __launch_bounds__(NTHR)
void conv_kernel(const float* __restrict__ x,
                 const float* __restrict__ bet_xy,
                 const float* __restrict__ bet_z,
                 const float* __restrict__ alpha,
                 float* __restrict__ out) {
    __shared__ __align__(16) float smem[SMEM_WORDS];
    float* Rb  = smem;                 // [2][NT][R_PL] (+16 pad)
    float* red = smem;                 // alias: pre-loop only
    float* ct  = smem + 512;           // alias: pre-loop only, [NT][16]

    const int t  = threadIdx.x;
    const int w0 = blockIdx.x * TW;
    const int h0 = blockIdx.y * TH;
    const int bz = blockIdx.z;
    const int b  = bz & 3;
    const int z0 = (bz >> 2) * ZCHUNK;
    const float INV = 0.3989422804014327f;
    const float4 z4 = make_float4(0.f, 0.f, 0.f, 0.f);

    // ---- exact global sum S (deterministic, identical in every block) ----
    float local = 0.f;
#pragma unroll
    for (int s = 0; s < 43; ++s) {
        int idx = t + s * NTHR;
        if (idx < NTAPS) {
            int bb = idx / 2025;
            int r  = idx % 2025;
            int dz = r / 225;
            int r2 = r % 225;
            int dh = r2 / 15;
            int dw = r2 % 15;
            float bxy = bet_xy[bb], bzv = bet_z[bb], al = alpha[bb];
            float zd = (float)(dz - 4), hd = (float)(dh - 7), wd = (float)(dw - 7);
            float az = expf(-zd * zd / (2.f * bzv * bzv)) * (INV / bzv);
            float gh = expf(-hd * hd / (2.f * bxy * bxy)) * (INV / bxy);
            float gw = expf(-wd * wd / (2.f * bxy * bxy)) * (INV / bxy);
            local += 1.f - expf(-al * az * gh * gw);
        }
    }
    red[t] = local;
    __syncthreads();
    for (int s = 128; s > 0; s >>= 1) {
        if (t < s && t + s < NTHR) red[t] += red[t + s];
        __syncthreads();
    }
    const float S = red[0];
    __syncthreads();

    // ---- own batch's coefficient table (65 values) into LDS ----
    if (t < NT * 13) {
        int n = t / 13;
        int k = t % 13;
        float bxy = bet_xy[b], bzv = bet_z[b], al = alpha[b];
        if (k < 8) {
            float d = (float)k;
            float g = expf(-d * d / (2.f * bxy * bxy)) * (INV / bxy);
            float p = g;
            for (int q = 0; q < n; ++q) p *= g;
            ct[n * 16 + k] = p;
        } else {
            float d = (float)(k - 8);
            float az = expf(-d * d / (2.f * bzv * bzv)) * (INV / bzv);
            float base = al * az;
            float p = base;
            for (int q = 0; q < n; ++q) p *= base;
            const float facs[NT] = {1.f, 2.f, 6.f, 24.f, 120.f};
            float sign = (n & 1) ? -1.f : 1.f;
            ct[n * 16 + k] = sign * p / (facs[n] * S);
        }
    }
    __syncthreads();

    // ---- hoist coefficients to wave-uniform scalars (SGPRs) ----
    float cg_[NT][8], cz_[NT][5];
#pragma unroll
    for (int n = 0; n < NT; ++n) {
#pragma unroll
        for (int k = 0; k < 8; ++k) cg_[n][k] = rfl(ct[n * 16 + k]);
#pragma unroll
        for (int k = 0; k < 5; ++k) cz_[n][k] = rfl(ct[n * 16 + 8 + k]);
    }
    __syncthreads();   // all ct/red reads done before R staging overwrites alias

    // ---- per-thread item (same (row, quad) for s1 and s2) ----
    const int r1 = t >> 4;          // 0..11
    const int q  = t & 15;          // 0..15
    const int gc0 = w0 - 8 + 4 * q;                 // aligned global col base
    const bool qok = (gc0 >= 0) && (gc0 <= W_ - 4); // quad fully in range
    const int gcc = min(max(gc0, 0), W_ - 4);       // safe (clamped) col base
    const int rbase = h0 + r1 - 7;
    const bool hint = (h0 >= 7) && (h0 + TH + 6 <= H_ - 1);  // all rows valid
    const float* xb = x + (size_t)b * (D_ * HW_);

    float4 acc[9];
#pragma unroll
    for (int k = 0; k < 9; ++k) acc[k] = z4;

#pragma unroll 1
    for (int p = 0; p <= NP; ++p) {
        __syncthreads();   // R[(p-1)&1] complete; R[p&1] free (prev s2 done)

        const int zi = z0 - 4 + p;
        const bool do_s1 = (p < NP) && (zi >= 0) && (zi < D_);

        // ---- s1 loads: issue early, consume after s2 (latency overlap) ----
        float4 pv[15];
        if (do_s1) {
            const float* pl = xb + (size_t)zi * HW_ + gcc;
            if (hint) {
                const float* pr = pl + (size_t)rbase * W_;
#pragma unroll
                for (int dh = 0; dh < 15; ++dh)
                    pv[dh] = *(const float4*)(pr + (size_t)dh * W_);
            } else {
#pragma unroll
                for (int dh = 0; dh < 15; ++dh) {
                    int gr = rbase + dh;
                    int grc = min(max(gr, 0), H_ - 1);
                    float4 v = *(const float4*)(pl + (size_t)grc * W_);
                    pv[dh] = ((unsigned)gr < (unsigned)H_) ? v : z4;
                }
            }
        }

        // ---- s2: w-conv + z-scatter for plane ziq = zi-1 from R[(p-1)&1] ----
        if (p >= 1) {
            const int ziq = zi - 1;
            if (ziq >= 0 && ziq < D_) {
                const float4* R4 = (const float4*)(Rb + ((p - 1) & 1) * RBUF);
                float4 u[5];
#pragma unroll
                for (int n = 0; n < NT; ++n) {
                    float win[20];
#pragma unroll
                    for (int i = 0; i < 5; ++i) {
                        float4 a = R4[n * (R_PL / 4) + t + i];
                        win[4 * i]     = a.x; win[4 * i + 1] = a.y;
                        win[4 * i + 2] = a.z; win[4 * i + 3] = a.w;
                    }
                    float c0 = cg_[n][0];
                    float4 qv;
                    qv.x = c0 * win[8];  qv.y = c0 * win[9];
                    qv.z = c0 * win[10]; qv.w = c0 * win[11];
#pragma unroll
                    for (int k = 1; k <= 7; ++k) {
                        float c = cg_[n][k];
                        qv.x = fmaf(c, win[8 - k]  + win[8 + k],  qv.x);
                        qv.y = fmaf(c, win[9 - k]  + win[9 + k],  qv.y);
                        qv.z = fmaf(c, win[10 - k] + win[10 + k], qv.z);
                        qv.w = fmaf(c, win[11 - k] + win[11 + k], qv.w);
                    }
                    if (n == 0) {
#pragma unroll
                        for (int j = 0; j < 5; ++j) {
                            float cz = cz_[0][j];
                            u[j].x = cz * qv.x; u[j].y = cz * qv.y;
                            u[j].z = cz * qv.z; u[j].w = cz * qv.w;
                        }
                    } else {
#pragma unroll
                        for (int j = 0; j < 5; ++j)
                            u[j] = f4fma(cz_[n][j], qv, u[j]);
                    }
                }
                acc[4] = f4add(acc[4], u[0]);
#pragma unroll
                for (int j = 1; j <= 4; ++j) {
                    acc[4 + j] = f4add(acc[4 + j], u[j]);
                    acc[4 - j] = f4add(acc[4 - j], u[j]);
                }
            }
            if (p - 1 >= 8 && q < 12) {
                int z = z0 + (p - 1 - 8);
                size_t o = ((size_t)(b * D_ + z) * H_ + (h0 + r1)) * W_ + (w0 + 4 * q);
                *(float4*)&out[o] = acc[0];
            }
#pragma unroll
            for (int k = 0; k < 8; ++k) acc[k] = acc[k + 1];
            acc[8] = z4;
        }

        // ---- s1 compute: fold taps, write R'[p&1] (dense: word 4t) ----
        if (do_s1) {
            float4 ctr = pv[7];
            float4 sp[7];
#pragma unroll
            for (int k = 1; k <= 7; ++k)
                sp[k - 1] = f4add(pv[7 - k], pv[7 + k]);
            float4* R4w = (float4*)(Rb + (p & 1) * RBUF);
#pragma unroll
            for (int n = 0; n < NT; ++n) {
                float c0 = cg_[n][0];
                float4 a;
                a.x = c0 * ctr.x; a.y = c0 * ctr.y;
                a.z = c0 * ctr.z; a.w = c0 * ctr.w;
#pragma unroll
                for (int k = 1; k <= 7; ++k) a = f4fma(cg_[n][k], sp[k - 1], a);
                R4w[n * (R_PL / 4) + t] = qok ? a : z4;
            }
        }
    }
}

extern "C" void kernel_launch(void* const* d_in, const int* in_sizes, int n_in,
                              void* d_out, int out_size, void* d_ws, size_t ws_size,
                              hipStream_t stream) {
    const float* x      = (const float*)d_in[0];
    const float* bet_xy = (const float*)d_in[1];
    const float* bet_z  = (const float*)d_in[2];
    const float* alpha  = (const float*)d_in[3];
    float* out = (float*)d_out;

    hipLaunchKernelGGL(conv_kernel, dim3(W_ / TW, H_ / TH, B_ * (D_ / ZCHUNK)),
                       dim3(NTHR), 0, stream, x, bet_xy, bet_z, alpha, out);
}

// Round 5
// 147.178 us; speedup vs baseline: 2.3273x; 2.3273x over previous
//
#include <hip/hip_runtime.h>
#include <math.h>

#define B_ 4
#define D_ 32
#define H_ 192
#define W_ 192
#define HW_ (H_ * W_)

#define NT 5            // Taylor terms p = 1..5

#define TW 48           // 12 real col-groups; stage-2 runs 16 groups (4 garbage)
#define TH 12
#define NTHR 256
#define ZCHUNK 16
#define NP (ZCHUNK + 8) // 24 staged planes; NP+1 = 25 pipelined iterations

#define XT_H 26         // TH + 14
#define XT_COLS 62      // TW + 14 staged cols
#define XT_W 64         // row stride in words: addr = 4*lane + 64*dh (dense)
#define XT_CELLS (XT_H * XT_COLS)   // 1612
#define NSEC 7
#define XT_SZ (XT_H * XT_W)         // 1664

// Stage-1 output R': per term, 12 rows x 16 quads (64 words)
#define R2_PL (TH * XT_W)     // 768 words per term-plane
#define RBUF (NT * R2_PL)     // 3840

#define SMEM_WORDS (2 * XT_SZ + 2 * RBUF + 16)   // 11024 words = 44.1 KB

#define NTAPS (B_ * 9 * 15 * 15)

__device__ inline float4 f4fma(float c, float4 a, float4 d) {
    d.x = fmaf(c, a.x, d.x); d.y = fmaf(c, a.y, d.y);
    d.z = fmaf(c, a.z, d.z); d.w = fmaf(c, a.w, d.w);
    return d;
}
__device__ inline float4 f4add(float4 a, float4 b) {
    a.x += b.x; a.y += b.y; a.z += b.z; a.w += b.w; return a;
}
__device__ inline float rfl(float x) {
    return __int_as_float(__builtin_amdgcn_readfirstlane(__float_as_int(x)));
}
// lane l <- lane l+N within each 16-lane DPP row; out-of-row -> 0.
template<int N>
__device__ inline float dpp_shl(float v) {
    return __int_as_float(__builtin_amdgcn_update_dpp(
        0, __float_as_int(v), 0x100 | N, 0xF, 0xF, true));
}

// h-first separable-Taylor blur (R2 structure) with DPP window assembly:
//   s1 (rt<192):  h-conv, reads xt[quad rt + 16*dh] (15 dense b128),
//                 writes R'[quad rt + 192n] (5 dense b128)
//   s2 (rt>=64):  w-conv reads ONLY its own quad per term (5 dense b128);
//                 the 18-float window comes from v_mov_dpp row_shl:1..4
//                 (16 groups/row == DPP row width; groups 12-15 garbage)
// LDS wave-ops per block-iter: 135 -> 75 (the binding LDS-pipe resource).
__global__ __launch_bounds__(NTHR)
void conv_kernel(const float* __restrict__ x,
                 const float* __restrict__ bet_xy,
                 const float* __restrict__ bet_z,
                 const float* __restrict__ alpha,
                 float* __restrict__ out) {
    __shared__ __align__(16) float smem[SMEM_WORDS];
    float* xtb = smem;                 // [2][XT_SZ]
    float* Rb  = smem + 2 * XT_SZ;     // [2][NT][R2_PL]
    float* red = smem;                 // alias: pre-loop only
    float* ct  = smem + 512;           // alias: pre-loop only, [NT][16]

    const int t  = threadIdx.x;
    const int w0 = blockIdx.x * TW;
    const int h0 = blockIdx.y * TH;
    const int bz = blockIdx.z;
    const int b  = bz & 3;
    const int z0 = (bz >> 2) * ZCHUNK;
    const float INV = 0.3989422804014327f;

    // ---- exact global sum S (deterministic, identical in every block) ----
    float local = 0.f;
#pragma unroll
    for (int s = 0; s < 32; ++s) {
        int idx = t + s * NTHR;
        if (idx < NTAPS) {
            int bb = idx / 2025;
            int r  = idx % 2025;
            int dz = r / 225;
            int r2 = r % 225;
            int dh = r2 / 15;
            int dw = r2 % 15;
            float bxy = bet_xy[bb], bzv = bet_z[bb], al = alpha[bb];
            float zd = (float)(dz - 4), hd = (float)(dh - 7), wd = (float)(dw - 7);
            float az = expf(-zd * zd / (2.f * bzv * bzv)) * (INV / bzv);
            float gh = expf(-hd * hd / (2.f * bxy * bxy)) * (INV / bxy);
            float gw = expf(-wd * wd / (2.f * bxy * bxy)) * (INV / bxy);
            local += 1.f - expf(-al * az * gh * gw);
        }
    }
    red[t] = local;
    __syncthreads();
    for (int s = 128; s > 0; s >>= 1) {
        if (t < s) red[t] += red[t + s];
        __syncthreads();
    }
    const float S = red[0];
    __syncthreads();

    // ---- own batch's coefficient table (65 values) into LDS ----
    if (t < NT * 13) {
        int n = t / 13;
        int k = t % 13;
        float bxy = bet_xy[b], bzv = bet_z[b], al = alpha[b];
        if (k < 8) {
            float d = (float)k;
            float g = expf(-d * d / (2.f * bxy * bxy)) * (INV / bxy);
            float p = g;
            for (int q = 0; q < n; ++q) p *= g;
            ct[n * 16 + k] = p;
        } else {
            float d = (float)(k - 8);
            float az = expf(-d * d / (2.f * bzv * bzv)) * (INV / bzv);
            float base = al * az;
            float p = base;
            for (int q = 0; q < n; ++q) p *= base;
            const float facs[NT] = {1.f, 2.f, 6.f, 24.f, 120.f};
            float sign = (n & 1) ? -1.f : 1.f;
            ct[n * 16 + k] = sign * p / (facs[n] * S);
        }
    }
    __syncthreads();

    // ---- hoist coefficients to wave-uniform scalars (SGPRs) ----
    float cg_[NT][8], cz_[NT][5];
#pragma unroll
    for (int n = 0; n < NT; ++n) {
#pragma unroll
        for (int k = 0; k < 8; ++k) cg_[n][k] = rfl(ct[n * 16 + k]);
#pragma unroll
        for (int k = 0; k < 5; ++k) cz_[n][k] = rfl(ct[n * 16 + 8 + k]);
    }
    __syncthreads();   // all ct/red reads done before xt staging overwrites alias

    // ---- staging descriptors (plane-invariant) ----
    const float* xb = x + (size_t)b * (D_ * HW_);
    int goff[NSEC], loff[NSEC];
#pragma unroll
    for (int k = 0; k < NSEC; ++k) {
        int i = t + k * NTHR;
        int r = i / XT_COLS, c = i - r * XT_COLS;
        int gh = h0 + r - 7, gw = w0 + c - 7;
        bool ok = (i < XT_CELLS) && gh >= 0 && gh < H_ && gw >= 0 && gw < W_;
        goff[k] = ok ? (gh * W_ + gw) : -1;
        loff[k] = (i < XT_CELLS) ? (r * XT_W + c) : (XT_SZ - 1);
    }
    // zero the 2 pad cols (62,63) of both xt buffers (read by quad-15 items)
    if (t < XT_H * 2) {
        int r = t >> 1, c = 62 + (t & 1);
        xtb[r * XT_W + c] = 0.f;
        xtb[XT_SZ + r * XT_W + c] = 0.f;
    }
    // pre-stage first plane (zi = z0-4) into xt buffer 0
    {
        int zi0 = z0 - 4;
        if (zi0 >= 0) {
#pragma unroll
            for (int k = 0; k < NSEC; ++k) {
                float v = 0.f;
                if (goff[k] >= 0) v = xb[(size_t)zi0 * HW_ + goff[k]];
                xtb[loff[k]] = v;
            }
        }
    }

    // ---- per-thread roles; rotate by 128 per adjacent block so co-resident
    //      blocks' heavy waves land on different SIMDs (128%16==0 keeps the
    //      lane<->group alignment DPP needs) ----
    const int bid = blockIdx.x + (int)gridDim.x * (blockIdx.y + (int)gridDim.y * blockIdx.z);
    const int rt  = (t + ((bid & 1) << 7)) & (NTHR - 1);

    // stage 1: 192 items = 12 rows x 16 quads; quad index = rt
    const bool s1act = (rt < 192);
    // stage 2: 192 items on rt in [64,256): l2 = rt-64; 12 rows x 16 groups
    const bool s2on = (rt >= 64);
    const int l2 = rt - 64;
    const int s2ro = l2 >> 4, s2cg = l2 & 15;
    const bool s2store = s2on && (s2cg < 12);

    float4 acc[9];
#pragma unroll
    for (int k = 0; k < 9; ++k) acc[k] = make_float4(0.f, 0.f, 0.f, 0.f);

#pragma unroll 1
    for (int p = 0; p <= NP; ++p) {
        __syncthreads();   // xt[p&1] staged; R'[(p-1)&1] complete; R'[p&1] free

        const int zi = z0 - 4 + p;
        const bool do_s1 = (p < NP) && (zi >= 0) && (zi < D_) && s1act;
        const int  zn    = zi + 1;
        const bool pvalid = (p + 1 < NP) && (zn >= 0) && (zn < D_);

        // prefetch next plane into registers (long-latency window = whole iter)
        float pv[NSEC];
        if (pvalid) {
            const float* xp = xb + (size_t)zn * HW_;
#pragma unroll
            for (int k = 0; k < NSEC; ++k) pv[k] = (goff[k] >= 0) ? xp[goff[k]] : 0.f;
        }

        // ---- stage 1: h-conv plane zi: xt[p&1] -> R'[p&1] (dense b128) ----
        if (do_s1) {
            const float4* x4 = (const float4*)(xtb + (p & 1) * XT_SZ + 4 * rt);
            float4* R4w = (float4*)(Rb + (p & 1) * RBUF);
            float4 ctr = x4[7 * 16];
            float4 sp[7];
#pragma unroll
            for (int k = 1; k <= 7; ++k)
                sp[k - 1] = f4add(x4[(7 - k) * 16], x4[(7 + k) * 16]);
#pragma unroll
            for (int n = 0; n < NT; ++n) {
                float c0 = cg_[n][0];
                float4 a;
                a.x = c0 * ctr.x; a.y = c0 * ctr.y;
                a.z = c0 * ctr.z; a.w = c0 * ctr.w;
#pragma unroll
                for (int k = 1; k <= 7; ++k) a = f4fma(cg_[n][k], sp[k - 1], a);
                R4w[rt + n * (R2_PL / 4)] = a;
            }
        }

        // ---- stage 2: w-conv + z-scatter, plane ziq = zi-1; own-quad read
        //      + DPP row_shl window assembly (no extra LDS traffic) ----
        if (p >= 1 && s2on) {
            const int ziq = zi - 1;
            if (ziq >= 0 && ziq < D_) {
                const float4* R4 = (const float4*)(Rb + ((p - 1) & 1) * RBUF) + l2;
                float4 u[5];
#pragma unroll
                for (int n = 0; n < NT; ++n) {
                    float4 A = R4[n * (R2_PL / 4)];
                    float win[18];
                    win[0]  = A.x; win[1]  = A.y; win[2]  = A.z; win[3]  = A.w;
                    win[4]  = dpp_shl<1>(A.x); win[5]  = dpp_shl<1>(A.y);
                    win[6]  = dpp_shl<1>(A.z); win[7]  = dpp_shl<1>(A.w);
                    win[8]  = dpp_shl<2>(A.x); win[9]  = dpp_shl<2>(A.y);
                    win[10] = dpp_shl<2>(A.z); win[11] = dpp_shl<2>(A.w);
                    win[12] = dpp_shl<3>(A.x); win[13] = dpp_shl<3>(A.y);
                    win[14] = dpp_shl<3>(A.z); win[15] = dpp_shl<3>(A.w);
                    win[16] = dpp_shl<4>(A.x); win[17] = dpp_shl<4>(A.y);
                    float c0 = cg_[n][0];
                    float4 qv;
                    qv.x = c0 * win[7];  qv.y = c0 * win[8];
                    qv.z = c0 * win[9];  qv.w = c0 * win[10];
#pragma unroll
                    for (int k = 1; k <= 7; ++k) {
                        float c = cg_[n][k];
                        qv.x = fmaf(c, win[7 - k]  + win[7 + k],  qv.x);
                        qv.y = fmaf(c, win[8 - k]  + win[8 + k],  qv.y);
                        qv.z = fmaf(c, win[9 - k]  + win[9 + k],  qv.z);
                        qv.w = fmaf(c, win[10 - k] + win[10 + k], qv.w);
                    }
                    if (n == 0) {
#pragma unroll
                        for (int j = 0; j < 5; ++j) {
                            float cz = cz_[0][j];
                            u[j].x = cz * qv.x; u[j].y = cz * qv.y;
                            u[j].z = cz * qv.z; u[j].w = cz * qv.w;
                        }
                    } else {
#pragma unroll
                        for (int j = 0; j < 5; ++j)
                            u[j] = f4fma(cz_[n][j], qv, u[j]);
                    }
                }
                acc[4] = f4add(acc[4], u[0]);
#pragma unroll
                for (int j = 1; j <= 4; ++j) {
                    acc[4 + j] = f4add(acc[4 + j], u[j]);
                    acc[4 - j] = f4add(acc[4 - j], u[j]);
                }
            }
            if (p - 1 >= 8 && s2store) {
                int z = z0 + (p - 1 - 8);
                size_t o = ((size_t)(b * D_ + z) * H_ + (h0 + s2ro)) * W_ + (w0 + 4 * s2cg);
                *(float4*)&out[o] = acc[0];
            }
#pragma unroll
            for (int k = 0; k < 8; ++k) acc[k] = acc[k + 1];
            acc[8] = make_float4(0.f, 0.f, 0.f, 0.f);
        }

        // write prefetched plane into xt[(p+1)&1]
        if (pvalid) {
            float* xn = xtb + ((p + 1) & 1) * XT_SZ;
#pragma unroll
            for (int k = 0; k < NSEC; ++k) xn[loff[k]] = pv[k];
        }
    }
}

extern "C" void kernel_launch(void* const* d_in, const int* in_sizes, int n_in,
                              void* d_out, int out_size, void* d_ws, size_t ws_size,
                              hipStream_t stream) {
    const float* x      = (const float*)d_in[0];
    const float* bet_xy = (const float*)d_in[1];
    const float* bet_z  = (const float*)d_in[2];
    const float* alpha  = (const float*)d_in[3];
    float* out = (float*)d_out;

    hipLaunchKernelGGL(conv_kernel, dim3(W_ / TW, H_ / TH, B_ * (D_ / ZCHUNK)),
                       dim3(NTHR), 0, stream, x, bet_xy, bet_z, alpha, out);
}